// Round 1
// baseline (187.361 us; speedup 1.0000x reference)
//
#include <hip/hip_runtime.h>

typedef __attribute__((ext_vector_type(8))) __bf16 bf16x8;
typedef __attribute__((ext_vector_type(8))) _Float16 f16x8;
typedef __attribute__((ext_vector_type(4))) _Float16 f16x4;
typedef __attribute__((ext_vector_type(4))) float f32x4;
typedef __attribute__((ext_vector_type(8))) unsigned short u16x8;
typedef __attribute__((ext_vector_type(4))) unsigned int u32x4;

#define MFMA_BF16(a, b, c) __builtin_amdgcn_mfma_f32_16x16x32_bf16((a), (b), (c), 0, 0, 0)
#define MFMA_F16(a, b, c)  __builtin_amdgcn_mfma_f32_16x16x32_f16((a), (b), (c), 0, 0, 0)
#define LOG2E 1.44269504088896340736f
#define QSCALE 0.18033688011112042f   // 0.125 * log2(e), folded into wq at cvt

__device__ __forceinline__ float b2f(unsigned short u) {
    union { unsigned int i; float f; } v; v.i = ((unsigned int)u) << 16; return v.f;
}
__device__ __forceinline__ unsigned short f2bf(float f) {
    union { float f; unsigned int i; } v; v.f = f;
    unsigned int u = v.i;
    return (unsigned short)((u + 0x7fffu + ((u >> 16) & 1u)) >> 16);
}

// async global->LDS, 16B/lane. HW dest = wave-uniform base + lane*16 (m104).
// Swizzle is applied on the GLOBAL side so conflict-free LDS layouts coexist with it.
__device__ __forceinline__ void gl_lds16(const void* g, void* l) {
    __builtin_amdgcn_global_load_lds(
        (const __attribute__((address_space(1))) void*)g,
        (__attribute__((address_space(3))) void*)l,
        16, 0, 0);
}

// ---------------- fp32 -> bf16 conversion of all 5 inputs; wq pre-scaled ----------
__global__ __launch_bounds__(256) void cvt_all(const float* __restrict__ x,
                                               const float* __restrict__ wq,
                                               const float* __restrict__ wk,
                                               const float* __restrict__ wv,
                                               const float* __restrict__ wo,
                                               unsigned short* __restrict__ xb,
                                               unsigned short* __restrict__ wqb,
                                               unsigned short* __restrict__ wkb,
                                               unsigned short* __restrict__ wvb,
                                               unsigned short* __restrict__ wob) {
    int id = blockIdx.x * 256 + threadIdx.x;  // [0, 1M)
    const float* src; unsigned short* dst; size_t off; float scl = 1.0f;
    if (id < 524288)      { src = x;  dst = xb;  off = (size_t)id * 8; }
    else if (id < 655360) { src = wq; dst = wqb; off = (size_t)(id - 524288) * 8; scl = QSCALE; }
    else if (id < 786432) { src = wk; dst = wkb; off = (size_t)(id - 655360) * 8; }
    else if (id < 917504) { src = wv; dst = wvb; off = (size_t)(id - 786432) * 8; }
    else                  { src = wo; dst = wob; off = (size_t)(id - 917504) * 8; }
    float4 a = *(const float4*)(src + off);
    float4 b = *(const float4*)(src + off + 4);
    u16x8 o;
    o[0] = f2bf(a.x * scl); o[1] = f2bf(a.y * scl); o[2] = f2bf(a.z * scl); o[3] = f2bf(a.w * scl);
    o[4] = f2bf(b.x * scl); o[5] = f2bf(b.y * scl); o[6] = f2bf(b.z * scl); o[7] = f2bf(b.w * scl);
    *(u16x8*)(dst + off) = o;
}

// ---------------- GEMM core: C[MxN] = A[MxK]*B[NxK]^T, bf16 in, fp32 accum --------
// 128x128 tile, BK=32, K=1024 fixed, A/B row stride 1024. LDS chunk (r,cpos) holds
// source chunk cpos^((r>>1)&3) -> frag ds_read_b128 is 2-way (free).
// MODE: 0 = bf16 out, 1 = f32 out, 2 = f16 out, 3 = bf16 out with fused RoPE
// (rows = tokens, cols = channels; pair partner via shfl_xor(1); scale pre-folded).
template <int MODE>
__device__ __forceinline__ void gemm128_bt(const unsigned short* __restrict__ A,
                                           const unsigned short* __restrict__ B,
                                           void* __restrict__ Cv,
                                           int m0, int n0, int ldc,
                                           unsigned short* As, unsigned short* Bs) {
    const int tid = threadIdx.x;
    const int w = tid >> 6, lane = tid & 63;
    const int quad = lane >> 4, l15 = lane & 15;
    const int wm = w & 1, wn = w >> 1;

    f32x4 acc[4][4];
#pragma unroll
    for (int mt = 0; mt < 4; ++mt)
#pragma unroll
        for (int nt = 0; nt < 4; ++nt) acc[mt][nt] = f32x4{0.f, 0.f, 0.f, 0.f};

    for (int k0 = 0; k0 < 1024; k0 += 32) {
        __syncthreads();
#pragma unroll
        for (int i = 0; i < 2; ++i) {
            int L = (w * 2 + i) * 64 + lane;      // chunk index in tile
            int r = L >> 2;
            int c = (L & 3) ^ ((r >> 1) & 3);     // swizzled source chunk
            gl_lds16(A + (size_t)(m0 + r) * 1024 + k0 + c * 8, As + L * 8);
            gl_lds16(B + (size_t)(n0 + r) * 1024 + k0 + c * 8, Bs + L * 8);
        }
        __syncthreads();

        bf16x8 af[4], bfr[4];
#pragma unroll
        for (int mt = 0; mt < 4; ++mt) {
            int row = wm * 64 + mt * 16 + l15;
            af[mt] = *(const bf16x8*)(As + row * 32 + (quad ^ ((row >> 1) & 3)) * 8);
        }
#pragma unroll
        for (int nt = 0; nt < 4; ++nt) {
            int row = wn * 64 + nt * 16 + l15;
            bfr[nt] = *(const bf16x8*)(Bs + row * 32 + (quad ^ ((row >> 1) & 3)) * 8);
        }
#pragma unroll
        for (int mt = 0; mt < 4; ++mt)
#pragma unroll
            for (int nt = 0; nt < 4; ++nt)
                acc[mt][nt] = MFMA_BF16(af[mt], bfr[nt], acc[mt][nt]);
    }

    // ---- fused RoPE (MODE 3): ch = nt*16+l15 (row-independent), pp = ch>>1 ----
    float invf[4], sgn = 0.f;
    if constexpr (MODE == 3) {
        sgn = (l15 & 1) ? 1.0f : -1.0f;   // odd lane: +p*sin ; even lane: -p*sin
#pragma unroll
        for (int nt = 0; nt < 4; ++nt)
            invf[nt] = exp2f(-0.41524101186092029f * (float)((nt * 16 + l15) >> 1));
    }

#pragma unroll
    for (int mt = 0; mt < 4; ++mt) {
        int grow = m0 + wm * 64 + mt * 16 + quad * 4;
#pragma unroll
        for (int nt = 0; nt < 4; ++nt) {
            int gcol = n0 + wn * 64 + nt * 16 + l15;
#pragma unroll
            for (int r = 0; r < 4; ++r) {
                float val = acc[mt][nt][r];
                size_t idx = (size_t)(grow + r) * ldc + gcol;
                if constexpr (MODE == 0) {
                    ((unsigned short*)Cv)[idx] = f2bf(val);
                } else if constexpr (MODE == 1) {
                    ((float*)Cv)[idx] = val;
                } else if constexpr (MODE == 2) {
                    _Float16 hv = (_Float16)val;
                    ((unsigned short*)Cv)[idx] = __builtin_bit_cast(unsigned short, hv);
                } else {
                    float p = __shfl_xor(val, 1);              // pair partner channel
                    float pos = (float)((grow + r) & 2047);    // seq position
                    float ang = pos * invf[nt];
                    float out = val * __cosf(ang) + sgn * p * __sinf(ang);
                    ((unsigned short*)Cv)[idx] = f2bf(out);
                }
            }
        }
    }
}

// Q/K: bf16 + fused RoPE (ldc 1024). V: C = Wv * X^T = V^T[ch][token] f16 (ldc 4096).
__global__ __launch_bounds__(256) void gemm_qkv(const unsigned short* __restrict__ X,
                                                const unsigned short* __restrict__ Wq,
                                                const unsigned short* __restrict__ Wk,
                                                const unsigned short* __restrict__ Wv,
                                                unsigned short* __restrict__ Qo,
                                                unsigned short* __restrict__ Ko,
                                                unsigned short* __restrict__ Vt) {
    __shared__ unsigned short As[128 * 32];
    __shared__ unsigned short Bs[128 * 32];
    int y = blockIdx.y;
    if (y < 16) {
        int sel = y >> 3;
        int m0 = blockIdx.x * 128;         // tokens
        int n0 = (y & 7) * 128;            // channels
        const unsigned short* B = sel ? Wk : Wq;
        unsigned short* C = sel ? Ko : Qo;
        gemm128_bt<3>(X, B, C, m0, n0, 1024, As, Bs);
    } else {
        int m0 = (y & 7) * 128;            // channels
        int n0 = blockIdx.x * 128;         // tokens
        gemm128_bt<2>(Wv, X, Vt, m0, n0, 4096, As, Bs);
    }
}

__global__ __launch_bounds__(256) void gemm_out(const unsigned short* __restrict__ A,
                                                const unsigned short* __restrict__ Wo,
                                                float* __restrict__ C) {
    __shared__ unsigned short As[128 * 32];
    __shared__ unsigned short Bs[128 * 32];
    gemm128_bt<1>(A, Wo, C, blockIdx.x * 128, blockIdx.y * 128, 1024, As, Bs);
}

// ---------------- Flash attention, causal, swapped-QK^T, P-in-registers -----------
// 256 blocks, 4 waves, Q-tile 128 rows (32 q-rows/wave, mt=2), KVBLK=64, K/V dbuf.
// Pair (qt, 15-qt) per block -> exactly 34 k-blocks per block (perfect balance).
// Swapped QK (mfma(K,Q)): lane l15 = q-row, so P stays lane-local; the PV MFMA's
// contraction index is permuted identically on P (pk word order) and V (b64-pair
// reads) so no cross-lane op and ZERO LDS traffic for P. Rowsum via ones-MFMA
// (A=pf => C rows = quad*4+r = q, matching the epilogue layout).
// K/V L2-resident via bh = xcd + 8*rr (4 bh/XCD = 3 MB working set).
#define FBODY(MASKED)                                                                   \
    {                                                                                   \
        bf16x8 kf[4][2];                                                                \
        _Pragma("unroll")                                                               \
        for (int nt = 0; nt < 4; ++nt) {                                                \
            int row = nt * 16 + l15;                                                    \
            const char* kp = (const char*)Ksb + row * 128;                              \
            int swk = row & 7;                                                          \
            kf[nt][0] = *(const bf16x8*)(kp + ((quad ^ swk) << 4));                     \
            kf[nt][1] = *(const bf16x8*)(kp + (((quad ^ 4) ^ swk) << 4));               \
        }                                                                               \
        f16x8 pf[2][2];                                                                 \
        _Pragma("unroll")                                                               \
        for (int mt = 0; mt < 2; ++mt) {                                                \
            f32x4 sc[4];                                                                \
            _Pragma("unroll")                                                           \
            for (int nt = 0; nt < 4; ++nt) {                                            \
                f32x4 z = f32x4{0.f, 0.f, 0.f, 0.f};                                    \
                z = MFMA_BF16(kf[nt][0], qf[mt][0], z);                                 \
                sc[nt] = MFMA_BF16(kf[nt][1], qf[mt][1], z);                            \
            }                                                                           \
            int qpos = qposw + mt * 16 + l15;                                           \
            unsigned pk[8];                                                             \
            _Pragma("unroll")                                                           \
            for (int nt = 0; nt < 4; ++nt) {                                            \
                float e[4];                                                             \
                _Pragma("unroll")                                                       \
                for (int r = 0; r < 4; ++r) {                                           \
                    float ev = exp2f(sc[nt][r]);                                        \
                    if (MASKED) {                                                       \
                        int kpos = kb * 64 + nt * 16 + quad * 4 + r;                    \
                        ev = (kpos > qpos) ? 0.f : ev;                                  \
                    }                                                                   \
                    e[r] = ev;                                                          \
                }                                                                       \
                pk[nt * 2 + 0] = __builtin_bit_cast(unsigned,                           \
                                     __builtin_amdgcn_cvt_pkrtz(e[0], e[1]));           \
                pk[nt * 2 + 1] = __builtin_bit_cast(unsigned,                           \
                                     __builtin_amdgcn_cvt_pkrtz(e[2], e[3]));           \
            }                                                                           \
            u32x4 pw0 = u32x4{pk[0], pk[1], pk[2], pk[3]};                              \
            u32x4 pw1 = u32x4{pk[4], pk[5], pk[6], pk[7]};                              \
            pf[mt][0] = __builtin_bit_cast(f16x8, pw0);                                 \
            pf[mt][1] = __builtin_bit_cast(f16x8, pw1);                                 \
            lacc[mt] = MFMA_F16(pf[mt][0], ones, lacc[mt]);                             \
            lacc[mt] = MFMA_F16(pf[mt][1], ones, lacc[mt]);                             \
        }                                                                               \
        _Pragma("unroll")                                                               \
        for (int nt = 0; nt < 4; ++nt) {                                                \
            int rowd = nt * 16 + l15;                                                   \
            const char* vp = (const char*)Vsb + rowd * 128;                             \
            int swv = rowd & 7;                                                         \
            int qh = quad >> 1, sub = (quad & 1) * 8;                                   \
            f16x4 a0 = *(const f16x4*)(vp + (((qh + 0) ^ swv) << 4) + sub);             \
            f16x4 a1 = *(const f16x4*)(vp + (((qh + 2) ^ swv) << 4) + sub);             \
            f16x8 v0 = __builtin_shufflevector(a0, a1, 0, 1, 2, 3, 4, 5, 6, 7);         \
            accO[0][nt] = MFMA_F16(pf[0][0], v0, accO[0][nt]);                          \
            accO[1][nt] = MFMA_F16(pf[1][0], v0, accO[1][nt]);                          \
            f16x4 b0 = *(const f16x4*)(vp + (((qh + 4) ^ swv) << 4) + sub);             \
            f16x4 b1 = *(const f16x4*)(vp + (((qh + 6) ^ swv) << 4) + sub);             \
            f16x8 v1 = __builtin_shufflevector(b0, b1, 0, 1, 2, 3, 4, 5, 6, 7);         \
            accO[0][nt] = MFMA_F16(pf[0][1], v1, accO[0][nt]);                          \
            accO[1][nt] = MFMA_F16(pf[1][1], v1, accO[1][nt]);                          \
        }                                                                               \
    }

__global__ __launch_bounds__(256) void flash_attn(const unsigned short* __restrict__ Q,
                                                  const unsigned short* __restrict__ Kb,
                                                  const unsigned short* __restrict__ Vt,
                                                  unsigned short* __restrict__ O) {
    int id = blockIdx.x;            // 256 blocks
    int xcd = id & 7;
    int sl = id >> 3;               // 0..31
    int rr = sl >> 3;               // 0..3
    int j  = sl & 7;                // pair {j, 15-j}
    int bh = xcd + 8 * rr;          // 4 bh per XCD -> K/V/Q slices L2-resident
    int b = bh >> 4, h = bh & 15;
    int tid = threadIdx.x, w = tid >> 6, lane = tid & 63;
    int quad = lane >> 4, l15 = lane & 15;

    __shared__ unsigned short Ks[2 * 4096];   // bf16 [key][d], chunk-swizzled, dbuf
    __shared__ unsigned short Vs[2 * 4096];   // f16  [d][key], chunk-swizzled, dbuf

    // staging: chunk L -> row r=L>>3, lds chunk-col cpos=L&7 holds src col cpos^(r&7)
    int L0 = w * 128 + lane;
    int L1 = L0 + 64;
    int r0 = L0 >> 3, c0 = (L0 & 7) ^ (r0 & 7);
    int r1 = L1 >> 3, c1 = (L1 & 7) ^ (r1 & 7);
    const unsigned short* Kg0 = Kb + (size_t)(b * 2048 + r0) * 1024 + h * 64 + c0 * 8;
    const unsigned short* Kg1 = Kb + (size_t)(b * 2048 + r1) * 1024 + h * 64 + c1 * 8;
    const unsigned short* Vg0 = Vt + (size_t)(h * 64 + r0) * 4096 + b * 2048 + c0 * 8;
    const unsigned short* Vg1 = Vt + (size_t)(h * 64 + r1) * 4096 + b * 2048 + c1 * 8;

    f16x8 ones;
#pragma unroll
    for (int t = 0; t < 8; ++t) ones[t] = (_Float16)1.0f;

#define STAGE(kb_, buf_)                                                    \
    {                                                                       \
        size_t ko = (size_t)(kb_) * 64 * 1024;                              \
        size_t vo = (size_t)(kb_) * 64;                                     \
        unsigned short* kd = Ks + (buf_) * 4096;                            \
        unsigned short* vd = Vs + (buf_) * 4096;                            \
        gl_lds16(Kg0 + ko, kd + L0 * 8);                                    \
        gl_lds16(Kg1 + ko, kd + L1 * 8);                                    \
        gl_lds16(Vg0 + vo, vd + L0 * 8);                                    \
        gl_lds16(Vg1 + vo, vd + L1 * 8);                                    \
    }

    for (int tp = 0; tp < 2; ++tp) {
        int qt = tp ? (15 - j) : j;
        int qrow0 = b * 2048 + qt * 128 + w * 32;
        int qposw = qt * 128 + w * 32;
        int nkb = 2 * qt + 2;

        STAGE(0, 0)

        bf16x8 qf[2][2];
#pragma unroll
        for (int mt = 0; mt < 2; ++mt) {
            const unsigned short* qp =
                Q + (size_t)(qrow0 + mt * 16 + l15) * 1024 + h * 64 + quad * 8;
            qf[mt][0] = *(const bf16x8*)qp;
            qf[mt][1] = *(const bf16x8*)(qp + 32);
        }

        f32x4 accO[2][4];
        f32x4 lacc[2];
#pragma unroll
        for (int mt = 0; mt < 2; ++mt) {
            lacc[mt] = f32x4{0.f, 0.f, 0.f, 0.f};
#pragma unroll
            for (int nt = 0; nt < 4; ++nt) accO[mt][nt] = f32x4{0.f, 0.f, 0.f, 0.f};
        }

        __asm__ volatile("s_waitcnt vmcnt(0)" ::: "memory");
        __builtin_amdgcn_s_barrier();
        __builtin_amdgcn_sched_barrier(0);

        int cur = 0;
        for (int kb = 0; kb < nkb; ++kb) {
            if (kb + 1 < nkb) STAGE(kb + 1, cur ^ 1)
            const unsigned short* Ksb = Ks + cur * 4096;
            const unsigned short* Vsb = Vs + cur * 4096;
            if (kb < nkb - 2) {
                FBODY(0)
            } else {
                FBODY(1)
            }
            __asm__ volatile("s_waitcnt vmcnt(0)" ::: "memory");
            __builtin_amdgcn_s_barrier();
            __builtin_amdgcn_sched_barrier(0);
            cur ^= 1;
        }

        // ---- epilogue: accO lane layout matches lacc (q = mt*16 + quad*4 + r) ----
#pragma unroll
        for (int mt = 0; mt < 2; ++mt) {
            float inv[4];
#pragma unroll
            for (int r = 0; r < 4; ++r) inv[r] = 1.0f / lacc[mt][r];
#pragma unroll
            for (int nt = 0; nt < 4; ++nt)
#pragma unroll
                for (int r = 0; r < 4; ++r)
                    O[(size_t)(qrow0 + mt * 16 + quad * 4 + r) * 1024 +
                      h * 64 + nt * 16 + l15] = f2bf(accO[mt][nt][r] * inv[r]);
        }
    }
#undef STAGE
}

extern "C" void kernel_launch(void* const* d_in, const int* in_sizes, int n_in,
                              void* d_out, int out_size, void* d_ws, size_t ws_size,
                              hipStream_t stream) {
    (void)in_sizes; (void)n_in; (void)out_size; (void)ws_size;
    const float* x  = (const float*)d_in[0];
    const float* wq = (const float*)d_in[1];
    const float* wk = (const float*)d_in[2];
    const float* wv = (const float*)d_in[3];
    const float* wo = (const float*)d_in[4];
    float* out = (float*)d_out;

    const size_t T = (size_t)4096 * 1024;
    const size_t W = (size_t)1024 * 1024;
    unsigned short* Q   = (unsigned short*)d_ws;
    unsigned short* K   = Q + T;
    unsigned short* Vt  = K + T;      // f16 [ch][token], ldc 4096
    unsigned short* xb  = Vt + T;
    unsigned short* AO  = xb;         // alias: xb dead after gemm_qkv, AO written by flash
    unsigned short* wqb = xb + T;
    unsigned short* wkb = wqb + W;
    unsigned short* wvb = wkb + W;
    unsigned short* wob = wvb + W;
    // ws use: 4*8MB + 4*2MB = 40MB

    cvt_all  <<<dim3(4096),   256, 0, stream>>>(x, wq, wk, wv, wo, xb, wqb, wkb, wvb, wob);
    gemm_qkv <<<dim3(32, 24), 256, 0, stream>>>(xb, wqb, wkb, wvb, Q, K, Vt);
    flash_attn<<<dim3(256),   256, 0, stream>>>(Q, K, Vt, AO);
    gemm_out <<<dim3(32, 8),  256, 0, stream>>>(AO, wob, out);
}